// Round 6
// baseline (188.399 us; speedup 1.0000x reference)
//
#include <hip/hip_runtime.h>
#include <cstdint>
#include <cstddef>

typedef __bf16 bf16x8 __attribute__((ext_vector_type(8)));
typedef float f32x4 __attribute__((ext_vector_type(4)));
typedef unsigned short ushort8 __attribute__((ext_vector_type(8)));

#define OUT_DIM 4096
#define IN_DIM 4096
#define NT 64  // K tiles of 64

// ---------------- helpers ----------------

__device__ __forceinline__ unsigned short f2bf(float f) {
  unsigned u = __float_as_uint(f);
  return (unsigned short)((u + 0x7FFFu + ((u >> 16) & 1u)) >> 16);
}

__device__ __forceinline__ void async_copy16(const void* g, void* l) {
  __builtin_amdgcn_global_load_lds(
      (const __attribute__((address_space(1))) unsigned int*)g,
      (__attribute__((address_space(3))) unsigned int*)l, 16, 0, 0);
}

// ---------------- weight build ----------------

// int4 dequant -> bf16 Wb directly. 8 weights/thread, 64 MB total traffic.
__global__ __launch_bounds__(256) void dequant_kernel(
    const int* __restrict__ packed, const float* __restrict__ scales,
    unsigned short* __restrict__ wb) {
  int idx = blockIdx.x * 256 + threadIdx.x;  // 4 packed int32 bytes -> 8 weights
  int4 p = reinterpret_cast<const int4*>(packed)[idx];
  float s = scales[idx >> 9];  // 512 int4-groups per row
  ushort8 o;
  o[0] = f2bf((float)((p.x & 15) - 8) * s);
  o[1] = f2bf((float)(((p.x >> 4) & 15) - 8) * s);
  o[2] = f2bf((float)((p.y & 15) - 8) * s);
  o[3] = f2bf((float)(((p.y >> 4) & 15) - 8) * s);
  o[4] = f2bf((float)((p.z & 15) - 8) * s);
  o[5] = f2bf((float)(((p.z >> 4) & 15) - 8) * s);
  o[6] = f2bf((float)((p.w & 15) - 8) * s);
  o[7] = f2bf((float)(((p.w >> 4) & 15) - 8) * s);
  *reinterpret_cast<ushort8*>(&wb[(size_t)idx * 8]) = o;
}

// outlier add directly into bf16 weights via 32-bit CAS on the containing
// word. Duplicated (row,col) pairs each retry-accumulate correctly.
__global__ __launch_bounds__(256) void scatter_bf16_kernel(
    const float* __restrict__ vals, const int* __restrict__ rows,
    const int* __restrict__ cols, unsigned short* __restrict__ wb, int nnz) {
  int i = blockIdx.x * 256 + threadIdx.x;
  if (i >= nnz) return;
  size_t idx = (size_t)rows[i] * IN_DIM + cols[i];
  unsigned int* word = (unsigned int*)(wb + (idx & ~(size_t)1));
  const bool hi = (idx & 1) != 0;
  const float v = vals[i];
  unsigned int old = *word, assumed;
  do {
    assumed = old;
    unsigned short h = hi ? (unsigned short)(assumed >> 16)
                          : (unsigned short)(assumed & 0xFFFFu);
    float f = __uint_as_float((unsigned)h << 16);  // bf16 -> f32 exact
    unsigned short nh = f2bf(f + v);
    unsigned int nw = hi ? ((assumed & 0x0000FFFFu) | ((unsigned)nh << 16))
                         : ((assumed & 0xFFFF0000u) | (unsigned)nh);
    old = atomicCAS(word, assumed, nw);
  } while (old != assumed);
}

__global__ __launch_bounds__(256) void cvt_kernel(
    const float* __restrict__ in, unsigned short* __restrict__ out) {
  int i = blockIdx.x * 256 + threadIdx.x;
  float4 a = reinterpret_cast<const float4*>(in)[2 * i];
  float4 b = reinterpret_cast<const float4*>(in)[2 * i + 1];
  ushort8 o;
  o[0] = f2bf(a.x); o[1] = f2bf(a.y); o[2] = f2bf(a.z); o[3] = f2bf(a.w);
  o[4] = f2bf(b.x); o[5] = f2bf(b.y); o[6] = f2bf(b.z); o[7] = f2bf(b.w);
  *reinterpret_cast<ushort8*>(&out[(size_t)i * 8]) = o;
}

// ---------------- GEMM: C[N][O] = A[N][K] * B[O][K]^T, 256x256 tile --------
// 8 waves, deep pipeline + REGISTER FRAG PREFETCH: each phase issues the
// NEXT phase's ds_read_b128 into an alternate E/O register set right after
// lgkmcnt(0), so LDS service overlaps the MFMA cluster (round-5 counters
// showed LDS (2260cy) and MFMA (2480cy) fully serialized at 4700cy/K-tile).
// DMA schedule / vmcnt ledger / barriers byte-identical to the verified
// round-3 kernel. Swizzle sigma(row)=(row>>1)&3 on 16B slots, both-sides.
//
// Frag set rotation:  phase: P1      P2      P3      P4
//   uses   (A,B):           aE,bE   aO,bE   aE,bO   aO,bO
//   prefetch:               aO<-kh0 aE<-kh1 aO<-kh1 aE<-kh0'  (next phase)
//                           mh1     mh0     mh1     mh0'
//                                   bO<-kh1         bE<-kh0'  (' = next tile)
// Coverage: every prefetch issues after the vmcnt(8)+barrier covering its
// slab (P2/P4 prefetches sit after that same phase's own vmcnt(8)).

#define SB(buf, op, kh) ((((buf) * 4) + ((op) * 2) + (kh)) * 16384)

#define STAGE(buf, op, kh, kt)                                              \
  do {                                                                      \
    const unsigned short* gsrc_ =                                           \
        (op) ? (const unsigned short*)((const char*)gA + dBA) : gA;         \
    const unsigned short* g_ = gsrc_ + (kt) * 64 + (kh) * 32;               \
    unsigned short* l_ =                                                    \
        (unsigned short*)((char*)lds + SB(buf, op, kh)) + wave * 512;       \
    async_copy16(g_, l_);                                                   \
    async_copy16(g_ + 128 * IN_DIM, l_ + 4096);                             \
  } while (0)

#define MFMA_ __builtin_amdgcn_mfma_f32_16x16x32_bf16

// A frag i: row = wm*128 + MH*64 + i*16 + lrow, byte = row*64 + lks*16 + slab
#define LDA4(d0, d1, d2, d3, BUF, KS, MH)                                   \
  d0 = *(const bf16x8*)(ldsc + (laneA + SB(BUF, 0, KS) + (MH) * 4096 + 0)); \
  d1 = *(const bf16x8*)(ldsc + (laneA + SB(BUF, 0, KS) + (MH) * 4096 + 1024)); \
  d2 = *(const bf16x8*)(ldsc + (laneA + SB(BUF, 0, KS) + (MH) * 4096 + 2048)); \
  d3 = *(const bf16x8*)(ldsc + (laneA + SB(BUF, 0, KS) + (MH) * 4096 + 3072))

#define LDB4(d0, d1, d2, d3, BUF, KS)                                       \
  d0 = *(const bf16x8*)(ldsc + (laneB + SB(BUF, 1, KS) + 0));               \
  d1 = *(const bf16x8*)(ldsc + (laneB + SB(BUF, 1, KS) + 1024));            \
  d2 = *(const bf16x8*)(ldsc + (laneB + SB(BUF, 1, KS) + 2048));            \
  d3 = *(const bf16x8*)(ldsc + (laneB + SB(BUF, 1, KS) + 3072))

#define MM16(MH, A0, A1, A2, A3, B0, B1, B2, B3)                            \
  acc[(MH) * 4 + 0][0] = MFMA_(A0, B0, acc[(MH) * 4 + 0][0], 0, 0, 0);      \
  acc[(MH) * 4 + 0][1] = MFMA_(A0, B1, acc[(MH) * 4 + 0][1], 0, 0, 0);      \
  acc[(MH) * 4 + 0][2] = MFMA_(A0, B2, acc[(MH) * 4 + 0][2], 0, 0, 0);      \
  acc[(MH) * 4 + 0][3] = MFMA_(A0, B3, acc[(MH) * 4 + 0][3], 0, 0, 0);      \
  acc[(MH) * 4 + 1][0] = MFMA_(A1, B0, acc[(MH) * 4 + 1][0], 0, 0, 0);      \
  acc[(MH) * 4 + 1][1] = MFMA_(A1, B1, acc[(MH) * 4 + 1][1], 0, 0, 0);      \
  acc[(MH) * 4 + 1][2] = MFMA_(A1, B2, acc[(MH) * 4 + 1][2], 0, 0, 0);      \
  acc[(MH) * 4 + 1][3] = MFMA_(A1, B3, acc[(MH) * 4 + 1][3], 0, 0, 0);      \
  acc[(MH) * 4 + 2][0] = MFMA_(A2, B0, acc[(MH) * 4 + 2][0], 0, 0, 0);      \
  acc[(MH) * 4 + 2][1] = MFMA_(A2, B1, acc[(MH) * 4 + 2][1], 0, 0, 0);      \
  acc[(MH) * 4 + 2][2] = MFMA_(A2, B2, acc[(MH) * 4 + 2][2], 0, 0, 0);      \
  acc[(MH) * 4 + 2][3] = MFMA_(A2, B3, acc[(MH) * 4 + 2][3], 0, 0, 0);      \
  acc[(MH) * 4 + 3][0] = MFMA_(A3, B0, acc[(MH) * 4 + 3][0], 0, 0, 0);      \
  acc[(MH) * 4 + 3][1] = MFMA_(A3, B1, acc[(MH) * 4 + 3][1], 0, 0, 0);      \
  acc[(MH) * 4 + 3][2] = MFMA_(A3, B2, acc[(MH) * 4 + 3][2], 0, 0, 0);      \
  acc[(MH) * 4 + 3][3] = MFMA_(A3, B3, acc[(MH) * 4 + 3][3], 0, 0, 0)

// STAGEST / PREF (last, variadic) are parenthesized macro calls; inner
// commas are protected. PREF issues the NEXT phase's frag reads.
#define PHASEX(STAGEST, DOWAIT, MH, A0, A1, A2, A3, B0, B1, B2, B3, ...)    \
  do {                                                                      \
    STAGEST;                                                                \
    if (DOWAIT) asm volatile("s_waitcnt vmcnt(8)" ::: "memory");            \
    __builtin_amdgcn_s_barrier();                                           \
    asm volatile("s_waitcnt lgkmcnt(0)" ::: "memory");                      \
    __builtin_amdgcn_sched_barrier(0);                                      \
    __VA_ARGS__;                                                            \
    __builtin_amdgcn_sched_barrier(0);                                      \
    __builtin_amdgcn_s_setprio(1);                                          \
    MM16(MH, A0, A1, A2, A3, B0, B1, B2, B3);                               \
    __builtin_amdgcn_s_setprio(0);                                          \
    __builtin_amdgcn_s_barrier();                                           \
  } while (0)

#define MINC(x) ((x) < NT ? (x) : (NT - 1))

#define TILE(BUF, t)                                                        \
  do {                                                                      \
    PHASEX(STAGE(1 - (BUF), 0, 1, MINC((t) + 1)), 0, 0,                     \
           aE0, aE1, aE2, aE3, bE0, bE1, bE2, bE3,                          \
           LDA4(aO0, aO1, aO2, aO3, BUF, 0, 1));                            \
    PHASEX(STAGE(1 - (BUF), 1, 1, MINC((t) + 1)), 1, 1,                     \
           aO0, aO1, aO2, aO3, bE0, bE1, bE2, bE3,                          \
           LDA4(aE0, aE1, aE2, aE3, BUF, 1, 0);                             \
           LDB4(bO0, bO1, bO2, bO3, BUF, 1));                               \
    PHASEX(STAGE(BUF, 0, 0, MINC((t) + 2)), 0, 0,                           \
           aE0, aE1, aE2, aE3, bO0, bO1, bO2, bO3,                          \
           LDA4(aO0, aO1, aO2, aO3, BUF, 1, 1));                            \
    PHASEX(STAGE(BUF, 1, 0, MINC((t) + 2)), 1, 1,                           \
           aO0, aO1, aO2, aO3, bO0, bO1, bO2, bO3,                          \
           LDA4(aE0, aE1, aE2, aE3, 1 - (BUF), 0, 0);                       \
           LDB4(bE0, bE1, bE2, bE3, 1 - (BUF), 0));                         \
  } while (0)

__global__ __launch_bounds__(512, 2) void gemm_kernel(
    const unsigned short* __restrict__ A,  // [4096][4096] bf16 (x)
    const unsigned short* __restrict__ B,  // [4096][4096] bf16 (W)
    float* __restrict__ C) {               // [4096][4096] fp32
  __shared__ __align__(16) unsigned short lds[65536];  // 128 KiB
  const char* ldsc = (const char*)lds;

  // 4x8 (bm x bn) super-tile per XCD for L2 locality; 256%8==0 -> bijective
  const int bid = blockIdx.x;
  const int xcd = bid & 7, i_ = bid >> 3;
  const int bm = (xcd >> 1) * 4 + (i_ >> 3);
  const int bn = (xcd & 1) * 8 + (i_ & 7);
  const int m0 = bm * 256, n0 = bn * 256;

  const int tid = threadIdx.x;
  const int wave = tid >> 6, lane = tid & 63;
  const int wm = wave >> 2, wn = wave & 3;  // 2M x 4N wave grid
  const int lrow = lane & 15, lk = lane >> 4;

  // staging: chunk0 = tid -> (row=tid>>2, phys slot=tid&3); chunk1 = +128.
  // SOURCE slot pre-swizzled so swizzled-read sees correct data (rule #21).
  const int r0 = tid >> 2, s0 = tid & 3;
  const int s0s = s0 ^ ((r0 >> 1) & 3);
  const unsigned short* gA = A + (size_t)(m0 + r0) * IN_DIM + s0s * 8;
  // uniform (SGPR) byte delta to the B staging source
  const ptrdiff_t dBA = ((const char*)B - (const char*)A) +
                        (ptrdiff_t)(n0 - m0) * IN_DIM * 2;

  // per-lane LDS byte bases (swizzle folded into lks)
  const int lks = lk ^ ((lrow >> 1) & 3);
  const int laneA = (wm * 128 + lrow) * 64 + lks * 16;
  const int laneB = (wn * 64 + lrow) * 64 + lks * 16;

  f32x4 acc[8][4];
#pragma unroll
  for (int mi = 0; mi < 8; ++mi)
#pragma unroll
    for (int ni = 0; ni < 4; ++ni) acc[mi][ni] = (f32x4){0.f, 0.f, 0.f, 0.f};

  bf16x8 aE0, aE1, aE2, aE3, aO0, aO1, aO2, aO3;
  bf16x8 bE0, bE1, bE2, bE3, bO0, bO1, bO2, bO3;

  // prologue: A0(0) B0(0) A1(0) B1(0) -> buf0; A0(1) B0(1) -> buf1.
  // empty-asm separators pin issue order (vmcnt counts issue order).
  STAGE(0, 0, 0, 0); STAGE(0, 1, 0, 0);
  asm volatile("" ::: "memory");
  STAGE(0, 0, 1, 0); STAGE(0, 1, 1, 0);
  asm volatile("" ::: "memory");
  STAGE(1, 0, 0, 1); STAGE(1, 1, 0, 1);
  asm volatile("s_waitcnt vmcnt(8)" ::: "memory");  // A0(0),B0(0) complete
  __builtin_amdgcn_s_barrier();

  // pre-read the first phase's fragments
  LDA4(aE0, aE1, aE2, aE3, 0, 0, 0);
  LDB4(bE0, bE1, bE2, bE3, 0, 0);

#pragma unroll 1
  for (int p = 0; p < NT / 2; ++p) {
    const int te = 2 * p;
    TILE(0, te);
    TILE(1, te + 1);
  }
  asm volatile("s_waitcnt vmcnt(0)" ::: "memory");  // drain DMA before endpgm

  // epilogue: D mapping col=lane&15, row=(lane>>4)*4+reg
#pragma unroll
  for (int mi = 0; mi < 8; ++mi)
#pragma unroll
    for (int ni = 0; ni < 4; ++ni) {
      int m = m0 + wm * 128 + mi * 16 + lk * 4;
      int n = n0 + wn * 64 + ni * 16 + lrow;
      float* cp = &C[(size_t)m * OUT_DIM + n];
#pragma unroll
      for (int r = 0; r < 4; ++r) cp[(size_t)r * OUT_DIM] = acc[mi][ni][r];
    }
}

// ---------------- launch ----------------

extern "C" void kernel_launch(void* const* d_in, const int* in_sizes, int n_in,
                              void* d_out, int out_size, void* d_ws, size_t ws_size,
                              hipStream_t stream) {
  const float* x      = (const float*)d_in[0];
  const int*   packed = (const int*)d_in[1];
  const float* scales = (const float*)d_in[2];
  const float* vals   = (const float*)d_in[3];
  const int*   rows   = (const int*)d_in[4];
  const int*   cols   = (const int*)d_in[5];
  float* out = (float*)d_out;

  const int nnz = in_sizes[3];

  // ws: [0,32MB) W bf16 | [32,64MB) X bf16
  char* ws = (char*)d_ws;
  const size_t MB = 1024 * 1024;
  unsigned short* Wb = (unsigned short*)ws;
  unsigned short* Xb = (unsigned short*)(ws + 32 * MB);

  // 1) int4 dequant -> bf16 Wb (no fp32 intermediate, no memset)
  dequant_kernel<<<8192, 256, 0, stream>>>(packed, scales, Wb);
  // 2) outlier residual added in-place via 32-bit CAS (duplicates safe)
  scatter_bf16_kernel<<<(nnz + 255) / 256, 256, 0, stream>>>(vals, rows, cols, Wb, nnz);
  // 3) x fp32 -> bf16
  cvt_kernel<<<8192, 256, 0, stream>>>(x, Xb);
  // 4) bf16 MFMA GEMM: out = Xb (4096x4096) * Wb^T
  gemm_kernel<<<256, 512, 0, stream>>>(Xb, Wb, out);
}

// Round 7
// 188.240 us; speedup vs baseline: 1.0008x; 1.0008x over previous
//
#include <hip/hip_runtime.h>
#include <cstdint>
#include <cstddef>

typedef __bf16 bf16x8 __attribute__((ext_vector_type(8)));
typedef float f32x4 __attribute__((ext_vector_type(4)));
typedef unsigned short ushort8 __attribute__((ext_vector_type(8)));

#define OUT_DIM 4096
#define IN_DIM 4096
#define NT 64  // K tiles of 64

// ---------------- helpers ----------------

__device__ __forceinline__ unsigned short f2bf(float f) {
  unsigned u = __float_as_uint(f);
  return (unsigned short)((u + 0x7FFFu + ((u >> 16) & 1u)) >> 16);
}

__device__ __forceinline__ void async_copy16(const void* g, void* l) {
  __builtin_amdgcn_global_load_lds(
      (const __attribute__((address_space(1))) unsigned int*)g,
      (__attribute__((address_space(3))) unsigned int*)l, 16, 0, 0);
}

// ---------------- weight build ----------------

// int4 dequant -> bf16 Wb directly. 8 weights/thread, 64 MB total traffic.
__global__ __launch_bounds__(256) void dequant_kernel(
    const int* __restrict__ packed, const float* __restrict__ scales,
    unsigned short* __restrict__ wb) {
  int idx = blockIdx.x * 256 + threadIdx.x;  // 4 packed int32 bytes -> 8 weights
  int4 p = reinterpret_cast<const int4*>(packed)[idx];
  float s = scales[idx >> 9];  // 512 int4-groups per row
  ushort8 o;
  o[0] = f2bf((float)((p.x & 15) - 8) * s);
  o[1] = f2bf((float)(((p.x >> 4) & 15) - 8) * s);
  o[2] = f2bf((float)((p.y & 15) - 8) * s);
  o[3] = f2bf((float)(((p.y >> 4) & 15) - 8) * s);
  o[4] = f2bf((float)((p.z & 15) - 8) * s);
  o[5] = f2bf((float)(((p.z >> 4) & 15) - 8) * s);
  o[6] = f2bf((float)((p.w & 15) - 8) * s);
  o[7] = f2bf((float)(((p.w >> 4) & 15) - 8) * s);
  *reinterpret_cast<ushort8*>(&wb[(size_t)idx * 8]) = o;
}

// outlier add directly into bf16 weights via 32-bit CAS on the containing
// word. Duplicated (row,col) pairs each retry-accumulate correctly.
__global__ __launch_bounds__(256) void scatter_bf16_kernel(
    const float* __restrict__ vals, const int* __restrict__ rows,
    const int* __restrict__ cols, unsigned short* __restrict__ wb, int nnz) {
  int i = blockIdx.x * 256 + threadIdx.x;
  if (i >= nnz) return;
  size_t idx = (size_t)rows[i] * IN_DIM + cols[i];
  unsigned int* word = (unsigned int*)(wb + (idx & ~(size_t)1));
  const bool hi = (idx & 1) != 0;
  const float v = vals[i];
  unsigned int old = *word, assumed;
  do {
    assumed = old;
    unsigned short h = hi ? (unsigned short)(assumed >> 16)
                          : (unsigned short)(assumed & 0xFFFFu);
    float f = __uint_as_float((unsigned)h << 16);  // bf16 -> f32 exact
    unsigned short nh = f2bf(f + v);
    unsigned int nw = hi ? ((assumed & 0x0000FFFFu) | ((unsigned)nh << 16))
                         : ((assumed & 0xFFFF0000u) | (unsigned)nh);
    old = atomicCAS(word, assumed, nw);
  } while (old != assumed);
}

__global__ __launch_bounds__(256) void cvt_kernel(
    const float* __restrict__ in, unsigned short* __restrict__ out) {
  int i = blockIdx.x * 256 + threadIdx.x;
  float4 a = reinterpret_cast<const float4*>(in)[2 * i];
  float4 b = reinterpret_cast<const float4*>(in)[2 * i + 1];
  ushort8 o;
  o[0] = f2bf(a.x); o[1] = f2bf(a.y); o[2] = f2bf(a.z); o[3] = f2bf(a.w);
  o[4] = f2bf(b.x); o[5] = f2bf(b.y); o[6] = f2bf(b.z); o[7] = f2bf(b.w);
  *reinterpret_cast<ushort8*>(&out[(size_t)i * 8]) = o;
}

// ---------------- GEMM: C[N][O] = A[N][K] * B[O][K]^T, 256x256 tile --------
// 8 waves, deep pipeline + E/O register frag rotation + COUNTED lgkmcnt:
// each phase issues the NEXT phase's ds_read_b128 right after the barrier,
// then waits lgkmcnt(N) where N = reads just issued. DS returns in order
// per wave, so all OLDER reads (this phase's MFMA operands) are complete
// while the N new reads stay outstanding THROUGH the MFMA cluster -> DS
// unit services them concurrently with the matrix pipe (round-6's
// lgkmcnt(0) full drain serialized them: 48% MfmaUtil).
//
// WAR ledger (reads vs DMA slab overwrite): reads of any slab are gated
// complete by the NEXT phase's counted wait, which precedes that wave's
// MFMA and end-barrier; any STAGE re-targeting the slab issues only after
// a later barrier -> all waves' reads done first. RAW ledger (DMA->read):
// identical issue positions to the verified round-3 kernel (vmcnt(8) at
// P2/P4 + barrier before first read of newly staged slabs).
// Swizzle sigma(row)=(row>>1)&3 on 16B slots, both-sides (rule #21).

#define SB(buf, op, kh) ((((buf) * 4) + ((op) * 2) + (kh)) * 16384)

#define STAGE(buf, op, kh, kt)                                              \
  do {                                                                      \
    const unsigned short* gsrc_ =                                           \
        (op) ? (const unsigned short*)((const char*)gA + dBA) : gA;         \
    const unsigned short* g_ = gsrc_ + (kt) * 64 + (kh) * 32;               \
    unsigned short* l_ =                                                    \
        (unsigned short*)((char*)lds + SB(buf, op, kh)) + wave * 512;       \
    async_copy16(g_, l_);                                                   \
    async_copy16(g_ + 128 * IN_DIM, l_ + 4096);                             \
  } while (0)

#define MFMA_ __builtin_amdgcn_mfma_f32_16x16x32_bf16

// A frag i: row = wm*128 + MH*64 + i*16 + lrow, byte = row*64 + lks*16 + slab
#define LDA4(d0, d1, d2, d3, BUF, KS, MH)                                   \
  d0 = *(const bf16x8*)(ldsc + (laneA + SB(BUF, 0, KS) + (MH) * 4096 + 0)); \
  d1 = *(const bf16x8*)(ldsc + (laneA + SB(BUF, 0, KS) + (MH) * 4096 + 1024)); \
  d2 = *(const bf16x8*)(ldsc + (laneA + SB(BUF, 0, KS) + (MH) * 4096 + 2048)); \
  d3 = *(const bf16x8*)(ldsc + (laneA + SB(BUF, 0, KS) + (MH) * 4096 + 3072))

#define LDB4(d0, d1, d2, d3, BUF, KS)                                       \
  d0 = *(const bf16x8*)(ldsc + (laneB + SB(BUF, 1, KS) + 0));               \
  d1 = *(const bf16x8*)(ldsc + (laneB + SB(BUF, 1, KS) + 1024));            \
  d2 = *(const bf16x8*)(ldsc + (laneB + SB(BUF, 1, KS) + 2048));            \
  d3 = *(const bf16x8*)(ldsc + (laneB + SB(BUF, 1, KS) + 3072))

#define MM16(MH, A0, A1, A2, A3, B0, B1, B2, B3)                            \
  acc[(MH) * 4 + 0][0] = MFMA_(A0, B0, acc[(MH) * 4 + 0][0], 0, 0, 0);      \
  acc[(MH) * 4 + 0][1] = MFMA_(A0, B1, acc[(MH) * 4 + 0][1], 0, 0, 0);      \
  acc[(MH) * 4 + 0][2] = MFMA_(A0, B2, acc[(MH) * 4 + 0][2], 0, 0, 0);      \
  acc[(MH) * 4 + 0][3] = MFMA_(A0, B3, acc[(MH) * 4 + 0][3], 0, 0, 0);      \
  acc[(MH) * 4 + 1][0] = MFMA_(A1, B0, acc[(MH) * 4 + 1][0], 0, 0, 0);      \
  acc[(MH) * 4 + 1][1] = MFMA_(A1, B1, acc[(MH) * 4 + 1][1], 0, 0, 0);      \
  acc[(MH) * 4 + 1][2] = MFMA_(A1, B2, acc[(MH) * 4 + 1][2], 0, 0, 0);      \
  acc[(MH) * 4 + 1][3] = MFMA_(A1, B3, acc[(MH) * 4 + 1][3], 0, 0, 0);      \
  acc[(MH) * 4 + 2][0] = MFMA_(A2, B0, acc[(MH) * 4 + 2][0], 0, 0, 0);      \
  acc[(MH) * 4 + 2][1] = MFMA_(A2, B1, acc[(MH) * 4 + 2][1], 0, 0, 0);      \
  acc[(MH) * 4 + 2][2] = MFMA_(A2, B2, acc[(MH) * 4 + 2][2], 0, 0, 0);      \
  acc[(MH) * 4 + 2][3] = MFMA_(A2, B3, acc[(MH) * 4 + 2][3], 0, 0, 0);      \
  acc[(MH) * 4 + 3][0] = MFMA_(A3, B0, acc[(MH) * 4 + 3][0], 0, 0, 0);      \
  acc[(MH) * 4 + 3][1] = MFMA_(A3, B1, acc[(MH) * 4 + 3][1], 0, 0, 0);      \
  acc[(MH) * 4 + 3][2] = MFMA_(A3, B2, acc[(MH) * 4 + 3][2], 0, 0, 0);      \
  acc[(MH) * 4 + 3][3] = MFMA_(A3, B3, acc[(MH) * 4 + 3][3], 0, 0, 0)

// Phase: stage DMA -> [vmcnt(8)] -> barrier -> issue NEXT-phase frag reads
// (__VA_ARGS__, LGN of them) -> counted lgkmcnt(LGN) -> MFMA -> barrier.
#define PHASEX(STAGEST, DOWAIT, LGN, MH, A0, A1, A2, A3, B0, B1, B2, B3, ...) \
  do {                                                                      \
    STAGEST;                                                                \
    if (DOWAIT) asm volatile("s_waitcnt vmcnt(8)" ::: "memory");            \
    __builtin_amdgcn_s_barrier();                                           \
    __VA_ARGS__;                                                            \
    __builtin_amdgcn_sched_barrier(0);                                      \
    asm volatile("s_waitcnt lgkmcnt(" #LGN ")" ::: "memory");               \
    __builtin_amdgcn_sched_barrier(0);                                      \
    __builtin_amdgcn_s_setprio(1);                                          \
    MM16(MH, A0, A1, A2, A3, B0, B1, B2, B3);                               \
    __builtin_amdgcn_s_setprio(0);                                          \
    __builtin_amdgcn_s_barrier();                                           \
  } while (0)

#define MINC(x) ((x) < NT ? (x) : (NT - 1))

#define TILE(BUF, t)                                                        \
  do {                                                                      \
    PHASEX(STAGE(1 - (BUF), 0, 1, MINC((t) + 1)), 0, 4, 0,                  \
           aE0, aE1, aE2, aE3, bE0, bE1, bE2, bE3,                          \
           LDA4(aO0, aO1, aO2, aO3, BUF, 0, 1));                            \
    PHASEX(STAGE(1 - (BUF), 1, 1, MINC((t) + 1)), 1, 8, 1,                  \
           aO0, aO1, aO2, aO3, bE0, bE1, bE2, bE3,                          \
           LDA4(aE0, aE1, aE2, aE3, BUF, 1, 0);                             \
           LDB4(bO0, bO1, bO2, bO3, BUF, 1));                               \
    PHASEX(STAGE(BUF, 0, 0, MINC((t) + 2)), 0, 4, 0,                        \
           aE0, aE1, aE2, aE3, bO0, bO1, bO2, bO3,                          \
           LDA4(aO0, aO1, aO2, aO3, BUF, 1, 1));                            \
    PHASEX(STAGE(BUF, 1, 0, MINC((t) + 2)), 1, 8, 1,                        \
           aO0, aO1, aO2, aO3, bO0, bO1, bO2, bO3,                          \
           LDA4(aE0, aE1, aE2, aE3, 1 - (BUF), 0, 0);                       \
           LDB4(bE0, bE1, bE2, bE3, 1 - (BUF), 0));                         \
  } while (0)

__global__ __launch_bounds__(512, 2) void gemm_kernel(
    const unsigned short* __restrict__ A,  // [4096][4096] bf16 (x)
    const unsigned short* __restrict__ B,  // [4096][4096] bf16 (W)
    float* __restrict__ C) {               // [4096][4096] fp32
  __shared__ __align__(16) unsigned short lds[65536];  // 128 KiB
  const char* ldsc = (const char*)lds;

  // 4x8 (bm x bn) super-tile per XCD for L2 locality; 256%8==0 -> bijective
  const int bid = blockIdx.x;
  const int xcd = bid & 7, i_ = bid >> 3;
  const int bm = (xcd >> 1) * 4 + (i_ >> 3);
  const int bn = (xcd & 1) * 8 + (i_ & 7);
  const int m0 = bm * 256, n0 = bn * 256;

  const int tid = threadIdx.x;
  const int wave = tid >> 6, lane = tid & 63;
  const int wm = wave >> 2, wn = wave & 3;  // 2M x 4N wave grid
  const int lrow = lane & 15, lk = lane >> 4;

  // staging: chunk0 = tid -> (row=tid>>2, phys slot=tid&3); chunk1 = +128.
  // SOURCE slot pre-swizzled so swizzled-read sees correct data (rule #21).
  const int r0 = tid >> 2, s0 = tid & 3;
  const int s0s = s0 ^ ((r0 >> 1) & 3);
  const unsigned short* gA = A + (size_t)(m0 + r0) * IN_DIM + s0s * 8;
  // uniform (SGPR) byte delta to the B staging source
  const ptrdiff_t dBA = ((const char*)B - (const char*)A) +
                        (ptrdiff_t)(n0 - m0) * IN_DIM * 2;

  // per-lane LDS byte bases (swizzle folded into lks)
  const int lks = lk ^ ((lrow >> 1) & 3);
  const int laneA = (wm * 128 + lrow) * 64 + lks * 16;
  const int laneB = (wn * 64 + lrow) * 64 + lks * 16;

  f32x4 acc[8][4];
#pragma unroll
  for (int mi = 0; mi < 8; ++mi)
#pragma unroll
    for (int ni = 0; ni < 4; ++ni) acc[mi][ni] = (f32x4){0.f, 0.f, 0.f, 0.f};

  bf16x8 aE0, aE1, aE2, aE3, aO0, aO1, aO2, aO3;
  bf16x8 bE0, bE1, bE2, bE3, bO0, bO1, bO2, bO3;

  // prologue: A0(0) B0(0) A1(0) B1(0) -> buf0; A0(1) B0(1) -> buf1.
  // empty-asm separators pin issue order (vmcnt counts issue order).
  STAGE(0, 0, 0, 0); STAGE(0, 1, 0, 0);
  asm volatile("" ::: "memory");
  STAGE(0, 0, 1, 0); STAGE(0, 1, 1, 0);
  asm volatile("" ::: "memory");
  STAGE(1, 0, 0, 1); STAGE(1, 1, 0, 1);
  asm volatile("s_waitcnt vmcnt(8)" ::: "memory");  // A0(0),B0(0) complete
  __builtin_amdgcn_s_barrier();

  // pre-read the first phase's fragments (drained by P1's lgkmcnt(4))
  LDA4(aE0, aE1, aE2, aE3, 0, 0, 0);
  LDB4(bE0, bE1, bE2, bE3, 0, 0);

#pragma unroll 1
  for (int p = 0; p < NT / 2; ++p) {
    const int te = 2 * p;
    TILE(0, te);
    TILE(1, te + 1);
  }
  // drain DMA + any outstanding frag prefetch before epilogue/endpgm
  asm volatile("s_waitcnt vmcnt(0) lgkmcnt(0)" ::: "memory");

  // epilogue: D mapping col=lane&15, row=(lane>>4)*4+reg
#pragma unroll
  for (int mi = 0; mi < 8; ++mi)
#pragma unroll
    for (int ni = 0; ni < 4; ++ni) {
      int m = m0 + wm * 128 + mi * 16 + lk * 4;
      int n = n0 + wn * 64 + ni * 16 + lrow;
      float* cp = &C[(size_t)m * OUT_DIM + n];
#pragma unroll
      for (int r = 0; r < 4; ++r) cp[(size_t)r * OUT_DIM] = acc[mi][ni][r];
    }
}

// ---------------- launch ----------------

extern "C" void kernel_launch(void* const* d_in, const int* in_sizes, int n_in,
                              void* d_out, int out_size, void* d_ws, size_t ws_size,
                              hipStream_t stream) {
  const float* x      = (const float*)d_in[0];
  const int*   packed = (const int*)d_in[1];
  const float* scales = (const float*)d_in[2];
  const float* vals   = (const float*)d_in[3];
  const int*   rows   = (const int*)d_in[4];
  const int*   cols   = (const int*)d_in[5];
  float* out = (float*)d_out;

  const int nnz = in_sizes[3];

  // ws: [0,32MB) W bf16 | [32,64MB) X bf16
  char* ws = (char*)d_ws;
  const size_t MB = 1024 * 1024;
  unsigned short* Wb = (unsigned short*)ws;
  unsigned short* Xb = (unsigned short*)(ws + 32 * MB);

  // 1) int4 dequant -> bf16 Wb (no fp32 intermediate, no memset)
  dequant_kernel<<<8192, 256, 0, stream>>>(packed, scales, Wb);
  // 2) outlier residual added in-place via 32-bit CAS (duplicates safe)
  scatter_bf16_kernel<<<(nnz + 255) / 256, 256, 0, stream>>>(vals, rows, cols, Wb, nnz);
  // 3) x fp32 -> bf16
  cvt_kernel<<<8192, 256, 0, stream>>>(x, Xb);
  // 4) bf16 MFMA GEMM: out = Xb (4096x4096) * Wb^T
  gemm_kernel<<<256, 512, 0, stream>>>(Xb, Wb, out);
}

// Round 8
// 185.147 us; speedup vs baseline: 1.0176x; 1.0167x over previous
//
#include <hip/hip_runtime.h>
#include <cstdint>
#include <cstddef>

typedef __bf16 bf16x8 __attribute__((ext_vector_type(8)));
typedef float f32x4 __attribute__((ext_vector_type(4)));
typedef unsigned short ushort8 __attribute__((ext_vector_type(8)));

#define OUT_DIM 4096
#define IN_DIM 4096
#define NT 64  // K tiles of 64

// ---------------- helpers ----------------

__device__ __forceinline__ unsigned short f2bf(float f) {
  unsigned u = __float_as_uint(f);
  return (unsigned short)((u + 0x7FFFu + ((u >> 16) & 1u)) >> 16);
}

__device__ __forceinline__ void async_copy16(const void* g, void* l) {
  __builtin_amdgcn_global_load_lds(
      (const __attribute__((address_space(1))) unsigned int*)g,
      (__attribute__((address_space(3))) unsigned int*)l, 16, 0, 0);
}

// ---------------- weight build ----------------

// int4 dequant -> bf16 Wb directly. 8 weights/thread, 64 MB total traffic.
__global__ __launch_bounds__(256) void dequant_kernel(
    const int* __restrict__ packed, const float* __restrict__ scales,
    unsigned short* __restrict__ wb) {
  int idx = blockIdx.x * 256 + threadIdx.x;  // 4 packed int32 bytes -> 8 weights
  int4 p = reinterpret_cast<const int4*>(packed)[idx];
  float s = scales[idx >> 9];  // 512 int4-groups per row
  ushort8 o;
  o[0] = f2bf((float)((p.x & 15) - 8) * s);
  o[1] = f2bf((float)(((p.x >> 4) & 15) - 8) * s);
  o[2] = f2bf((float)((p.y & 15) - 8) * s);
  o[3] = f2bf((float)(((p.y >> 4) & 15) - 8) * s);
  o[4] = f2bf((float)((p.z & 15) - 8) * s);
  o[5] = f2bf((float)(((p.z >> 4) & 15) - 8) * s);
  o[6] = f2bf((float)((p.w & 15) - 8) * s);
  o[7] = f2bf((float)(((p.w >> 4) & 15) - 8) * s);
  *reinterpret_cast<ushort8*>(&wb[(size_t)idx * 8]) = o;
}

// outlier add directly into bf16 weights via 32-bit CAS on the containing
// word. Duplicated (row,col) pairs each retry-accumulate correctly.
__global__ __launch_bounds__(256) void scatter_bf16_kernel(
    const float* __restrict__ vals, const int* __restrict__ rows,
    const int* __restrict__ cols, unsigned short* __restrict__ wb, int nnz) {
  int i = blockIdx.x * 256 + threadIdx.x;
  if (i >= nnz) return;
  size_t idx = (size_t)rows[i] * IN_DIM + cols[i];
  unsigned int* word = (unsigned int*)(wb + (idx & ~(size_t)1));
  const bool hi = (idx & 1) != 0;
  const float v = vals[i];
  unsigned int old = *word, assumed;
  do {
    assumed = old;
    unsigned short h = hi ? (unsigned short)(assumed >> 16)
                          : (unsigned short)(assumed & 0xFFFFu);
    float f = __uint_as_float((unsigned)h << 16);  // bf16 -> f32 exact
    unsigned short nh = f2bf(f + v);
    unsigned int nw = hi ? ((assumed & 0x0000FFFFu) | ((unsigned)nh << 16))
                         : ((assumed & 0xFFFF0000u) | (unsigned)nh);
    old = atomicCAS(word, assumed, nw);
  } while (old != assumed);
}

__global__ __launch_bounds__(256) void cvt_kernel(
    const float* __restrict__ in, unsigned short* __restrict__ out) {
  int i = blockIdx.x * 256 + threadIdx.x;
  float4 a = reinterpret_cast<const float4*>(in)[2 * i];
  float4 b = reinterpret_cast<const float4*>(in)[2 * i + 1];
  ushort8 o;
  o[0] = f2bf(a.x); o[1] = f2bf(a.y); o[2] = f2bf(a.z); o[3] = f2bf(a.w);
  o[4] = f2bf(b.x); o[5] = f2bf(b.y); o[6] = f2bf(b.z); o[7] = f2bf(b.w);
  *reinterpret_cast<ushort8*>(&out[(size_t)i * 8]) = o;
}

// ---------------- GEMM: C[N][O] = A[N][K] * B[O][K]^T, 256x256 tile --------
// 8 waves, m201-exact phase skeleton: per phase
//   {ds_read THIS phase's frags} {stage 1 slab} [vmcnt(8)]
//   barrier; lgkmcnt(0); setprio(1); 16 MFMA; setprio(0); barrier;
// Reads issue BEFORE the barrier -> LDS services them during the barrier
// straggler window; lgkm(0) pays only the residue. B-frags (read in P1/P3)
// persist through P2/P4.
//
// Ledger (tile t, buf=t%2): P1 reads A-kh0(mh0)+B-kh0, stages A-kh1(t+1);
// P2 reads A-kh0(mh1), stages B-kh1(t+1), vmcnt(8); P3 reads A-kh1(mh0)+
// B-kh1, stages A-kh0(t+2); P4 reads A-kh1(mh1), stages B-kh0(t+2),
// vmcnt(8). In-flight depth 12; vmcnt(8)@P2 forces A/B-kh1(t) complete
// (read at P3(t), after a barrier); vmcnt(8)@P4 forces A/B-kh0(t+1)
// (read at P1(t+1)). WAR: every slab's reads drain at its phase's lgkm(0),
// >=1 barrier before any re-stage of that slab.
// Swizzle sigma(row)=(row>>1)&3 on 16B slots, both-sides (rule #21).

#define SB(buf, op, kh) ((((buf) * 4) + ((op) * 2) + (kh)) * 16384)

#define STAGE(buf, op, kh, kt)                                              \
  do {                                                                      \
    const unsigned short* gsrc_ =                                           \
        (op) ? (const unsigned short*)((const char*)gA + dBA) : gA;         \
    const unsigned short* g_ = gsrc_ + (kt) * 64 + (kh) * 32;               \
    unsigned short* l_ =                                                    \
        (unsigned short*)((char*)lds + SB(buf, op, kh)) + wave * 512;       \
    async_copy16(g_, l_);                                                   \
    async_copy16(g_ + 128 * IN_DIM, l_ + 4096);                             \
  } while (0)

#define MFMA_ __builtin_amdgcn_mfma_f32_16x16x32_bf16

// A frag i: row = wm*128 + MH*64 + i*16 + lrow, byte = row*64 + lks*16 + slab
#define LDA4(d0, d1, d2, d3, BUF, KS, MH)                                   \
  d0 = *(const bf16x8*)(ldsc + (laneA + SB(BUF, 0, KS) + (MH) * 4096 + 0)); \
  d1 = *(const bf16x8*)(ldsc + (laneA + SB(BUF, 0, KS) + (MH) * 4096 + 1024)); \
  d2 = *(const bf16x8*)(ldsc + (laneA + SB(BUF, 0, KS) + (MH) * 4096 + 2048)); \
  d3 = *(const bf16x8*)(ldsc + (laneA + SB(BUF, 0, KS) + (MH) * 4096 + 3072))

#define LDB4(d0, d1, d2, d3, BUF, KS)                                       \
  d0 = *(const bf16x8*)(ldsc + (laneB + SB(BUF, 1, KS) + 0));               \
  d1 = *(const bf16x8*)(ldsc + (laneB + SB(BUF, 1, KS) + 1024));            \
  d2 = *(const bf16x8*)(ldsc + (laneB + SB(BUF, 1, KS) + 2048));            \
  d3 = *(const bf16x8*)(ldsc + (laneB + SB(BUF, 1, KS) + 3072))

#define MM16(MH, A0, A1, A2, A3, B0, B1, B2, B3)                            \
  acc[(MH) * 4 + 0][0] = MFMA_(A0, B0, acc[(MH) * 4 + 0][0], 0, 0, 0);      \
  acc[(MH) * 4 + 0][1] = MFMA_(A0, B1, acc[(MH) * 4 + 0][1], 0, 0, 0);      \
  acc[(MH) * 4 + 0][2] = MFMA_(A0, B2, acc[(MH) * 4 + 0][2], 0, 0, 0);      \
  acc[(MH) * 4 + 0][3] = MFMA_(A0, B3, acc[(MH) * 4 + 0][3], 0, 0, 0);      \
  acc[(MH) * 4 + 1][0] = MFMA_(A1, B0, acc[(MH) * 4 + 1][0], 0, 0, 0);      \
  acc[(MH) * 4 + 1][1] = MFMA_(A1, B1, acc[(MH) * 4 + 1][1], 0, 0, 0);      \
  acc[(MH) * 4 + 1][2] = MFMA_(A1, B2, acc[(MH) * 4 + 1][2], 0, 0, 0);      \
  acc[(MH) * 4 + 1][3] = MFMA_(A1, B3, acc[(MH) * 4 + 1][3], 0, 0, 0);      \
  acc[(MH) * 4 + 2][0] = MFMA_(A2, B0, acc[(MH) * 4 + 2][0], 0, 0, 0);      \
  acc[(MH) * 4 + 2][1] = MFMA_(A2, B1, acc[(MH) * 4 + 2][1], 0, 0, 0);      \
  acc[(MH) * 4 + 2][2] = MFMA_(A2, B2, acc[(MH) * 4 + 2][2], 0, 0, 0);      \
  acc[(MH) * 4 + 2][3] = MFMA_(A2, B3, acc[(MH) * 4 + 2][3], 0, 0, 0);      \
  acc[(MH) * 4 + 3][0] = MFMA_(A3, B0, acc[(MH) * 4 + 3][0], 0, 0, 0);      \
  acc[(MH) * 4 + 3][1] = MFMA_(A3, B1, acc[(MH) * 4 + 3][1], 0, 0, 0);      \
  acc[(MH) * 4 + 3][2] = MFMA_(A3, B2, acc[(MH) * 4 + 3][2], 0, 0, 0);      \
  acc[(MH) * 4 + 3][3] = MFMA_(A3, B3, acc[(MH) * 4 + 3][3], 0, 0, 0)

// 8-read phase: A(mh) + B(kh) frags, then MFMA. B-frags persist to the
// following 4-read phase.
#define PHASE8(BUF, KS, MH, STAGEST, DOWAIT)                                \
  do {                                                                      \
    bf16x8 a0_, a1_, a2_, a3_;                                              \
    LDA4(a0_, a1_, a2_, a3_, BUF, KS, MH);                                  \
    LDB4(bB0, bB1, bB2, bB3, BUF, KS);                                      \
    STAGEST;                                                                \
    if (DOWAIT) asm volatile("s_waitcnt vmcnt(8)" ::: "memory");            \
    __builtin_amdgcn_s_barrier();                                           \
    asm volatile("s_waitcnt lgkmcnt(0)" ::: "memory");                      \
    __builtin_amdgcn_s_setprio(1);                                          \
    MM16(MH, a0_, a1_, a2_, a3_, bB0, bB1, bB2, bB3);                       \
    __builtin_amdgcn_s_setprio(0);                                          \
    __builtin_amdgcn_s_barrier();                                           \
  } while (0)

// 4-read phase: A(mh) frags only; reuses persistent B-frags.
#define PHASE4(BUF, KS, MH, STAGEST, DOWAIT)                                \
  do {                                                                      \
    bf16x8 a0_, a1_, a2_, a3_;                                              \
    LDA4(a0_, a1_, a2_, a3_, BUF, KS, MH);                                  \
    STAGEST;                                                                \
    if (DOWAIT) asm volatile("s_waitcnt vmcnt(8)" ::: "memory");            \
    __builtin_amdgcn_s_barrier();                                           \
    asm volatile("s_waitcnt lgkmcnt(0)" ::: "memory");                      \
    __builtin_amdgcn_s_setprio(1);                                          \
    MM16(MH, a0_, a1_, a2_, a3_, bB0, bB1, bB2, bB3);                       \
    __builtin_amdgcn_s_setprio(0);                                          \
    __builtin_amdgcn_s_barrier();                                           \
  } while (0)

#define MINC(x) ((x) < NT ? (x) : (NT - 1))

#define TILE(BUF, t)                                                        \
  do {                                                                      \
    PHASE8(BUF, 0, 0, STAGE(1 - (BUF), 0, 1, MINC((t) + 1)), 0);            \
    PHASE4(BUF, 0, 1, STAGE(1 - (BUF), 1, 1, MINC((t) + 1)), 1);            \
    PHASE8(BUF, 1, 0, STAGE(BUF, 0, 0, MINC((t) + 2)), 0);                  \
    PHASE4(BUF, 1, 1, STAGE(BUF, 1, 0, MINC((t) + 2)), 1);                  \
  } while (0)

__global__ __launch_bounds__(512, 2) void gemm_kernel(
    const unsigned short* __restrict__ A,  // [4096][4096] bf16 (x)
    const unsigned short* __restrict__ B,  // [4096][4096] bf16 (W)
    float* __restrict__ C) {               // [4096][4096] fp32
  __shared__ __align__(16) unsigned short lds[65536];  // 128 KiB
  const char* ldsc = (const char*)lds;

  // 4x8 (bm x bn) super-tile per XCD for L2 locality; 256%8==0 -> bijective
  const int bid = blockIdx.x;
  const int xcd = bid & 7, i_ = bid >> 3;
  const int bm = (xcd >> 1) * 4 + (i_ >> 3);
  const int bn = (xcd & 1) * 8 + (i_ & 7);
  const int m0 = bm * 256, n0 = bn * 256;

  const int tid = threadIdx.x;
  const int wave = tid >> 6, lane = tid & 63;
  const int wm = wave >> 2, wn = wave & 3;  // 2M x 4N wave grid
  const int lrow = lane & 15, lk = lane >> 4;

  // staging: chunk0 = tid -> (row=tid>>2, phys slot=tid&3); chunk1 = +128.
  // SOURCE slot pre-swizzled so swizzled-read sees correct data (rule #21).
  const int r0 = tid >> 2, s0 = tid & 3;
  const int s0s = s0 ^ ((r0 >> 1) & 3);
  const unsigned short* gA = A + (size_t)(m0 + r0) * IN_DIM + s0s * 8;
  // uniform (SGPR) byte delta to the B staging source
  const ptrdiff_t dBA = ((const char*)B - (const char*)A) +
                        (ptrdiff_t)(n0 - m0) * IN_DIM * 2;

  // per-lane LDS byte bases (swizzle folded into lks)
  const int lks = lk ^ ((lrow >> 1) & 3);
  const int laneA = (wm * 128 + lrow) * 64 + lks * 16;
  const int laneB = (wn * 64 + lrow) * 64 + lks * 16;

  f32x4 acc[8][4];
#pragma unroll
  for (int mi = 0; mi < 8; ++mi)
#pragma unroll
    for (int ni = 0; ni < 4; ++ni) acc[mi][ni] = (f32x4){0.f, 0.f, 0.f, 0.f};

  bf16x8 bB0, bB1, bB2, bB3;

  // prologue: A0(0) B0(0) A1(0) B1(0) -> buf0; A0(1) B0(1) -> buf1.
  // empty-asm separators pin issue order (vmcnt counts issue order).
  STAGE(0, 0, 0, 0); STAGE(0, 1, 0, 0);
  asm volatile("" ::: "memory");
  STAGE(0, 0, 1, 0); STAGE(0, 1, 1, 0);
  asm volatile("" ::: "memory");
  STAGE(1, 0, 0, 1); STAGE(1, 1, 0, 1);
  asm volatile("s_waitcnt vmcnt(8)" ::: "memory");  // A0(0),B0(0) complete
  __builtin_amdgcn_s_barrier();

#pragma unroll 1
  for (int p = 0; p < NT / 2; ++p) {
    const int te = 2 * p;
    TILE(0, te);
    TILE(1, te + 1);
  }
  // drain DMA before epilogue/endpgm
  asm volatile("s_waitcnt vmcnt(0) lgkmcnt(0)" ::: "memory");

  // epilogue: D mapping col=lane&15, row=(lane>>4)*4+reg
#pragma unroll
  for (int mi = 0; mi < 8; ++mi)
#pragma unroll
    for (int ni = 0; ni < 4; ++ni) {
      int m = m0 + wm * 128 + mi * 16 + lk * 4;
      int n = n0 + wn * 64 + ni * 16 + lrow;
      float* cp = &C[(size_t)m * OUT_DIM + n];
#pragma unroll
      for (int r = 0; r < 4; ++r) cp[(size_t)r * OUT_DIM] = acc[mi][ni][r];
    }
}

// ---------------- launch ----------------

extern "C" void kernel_launch(void* const* d_in, const int* in_sizes, int n_in,
                              void* d_out, int out_size, void* d_ws, size_t ws_size,
                              hipStream_t stream) {
  const float* x      = (const float*)d_in[0];
  const int*   packed = (const int*)d_in[1];
  const float* scales = (const float*)d_in[2];
  const float* vals   = (const float*)d_in[3];
  const int*   rows   = (const int*)d_in[4];
  const int*   cols   = (const int*)d_in[5];
  float* out = (float*)d_out;

  const int nnz = in_sizes[3];

  // ws: [0,32MB) W bf16 | [32,64MB) X bf16
  char* ws = (char*)d_ws;
  const size_t MB = 1024 * 1024;
  unsigned short* Wb = (unsigned short*)ws;
  unsigned short* Xb = (unsigned short*)(ws + 32 * MB);

  // 1) int4 dequant -> bf16 Wb (no fp32 intermediate, no memset)
  dequant_kernel<<<8192, 256, 0, stream>>>(packed, scales, Wb);
  // 2) outlier residual added in-place via 32-bit CAS (duplicates safe)
  scatter_bf16_kernel<<<(nnz + 255) / 256, 256, 0, stream>>>(vals, rows, cols, Wb, nnz);
  // 3) x fp32 -> bf16
  cvt_kernel<<<8192, 256, 0, stream>>>(x, Xb);
  // 4) bf16 MFMA GEMM: out = Xb (4096x4096) * Wb^T
  gemm_kernel<<<256, 512, 0, stream>>>(Xb, Wb, out);
}

// Round 9
// 179.909 us; speedup vs baseline: 1.0472x; 1.0291x over previous
//
#include <hip/hip_runtime.h>
#include <cstdint>
#include <cstddef>

typedef __bf16 bf16x8 __attribute__((ext_vector_type(8)));
typedef float f32x4 __attribute__((ext_vector_type(4)));
typedef unsigned short ushort8 __attribute__((ext_vector_type(8)));

#define OUT_DIM 4096
#define IN_DIM 4096
#define NT 64  // K tiles of 64

// ---------------- helpers ----------------

__device__ __forceinline__ unsigned short f2bf(float f) {
  unsigned u = __float_as_uint(f);
  return (unsigned short)((u + 0x7FFFu + ((u >> 16) & 1u)) >> 16);
}

__device__ __forceinline__ void async_copy16(const void* g, void* l) {
  __builtin_amdgcn_global_load_lds(
      (const __attribute__((address_space(1))) unsigned int*)g,
      (__attribute__((address_space(3))) unsigned int*)l, 16, 0, 0);
}

// ---------------- weight build ----------------

// merged: blocks [0,8192) = int4 dequant -> bf16 Wb; blocks [8192,16384) =
// x fp32 -> bf16 Xb. One launch instead of two.
__global__ __launch_bounds__(256) void prep_kernel(
    const int* __restrict__ packed, const float* __restrict__ scales,
    unsigned short* __restrict__ wb, const float* __restrict__ x,
    unsigned short* __restrict__ xb) {
  int b = blockIdx.x;
  if (b < 8192) {
    int idx = b * 256 + threadIdx.x;  // 4 packed int32 bytes -> 8 weights
    int4 p = reinterpret_cast<const int4*>(packed)[idx];
    float s = scales[idx >> 9];  // 512 int4-groups per row
    ushort8 o;
    o[0] = f2bf((float)((p.x & 15) - 8) * s);
    o[1] = f2bf((float)(((p.x >> 4) & 15) - 8) * s);
    o[2] = f2bf((float)((p.y & 15) - 8) * s);
    o[3] = f2bf((float)(((p.y >> 4) & 15) - 8) * s);
    o[4] = f2bf((float)((p.z & 15) - 8) * s);
    o[5] = f2bf((float)(((p.z >> 4) & 15) - 8) * s);
    o[6] = f2bf((float)((p.w & 15) - 8) * s);
    o[7] = f2bf((float)(((p.w >> 4) & 15) - 8) * s);
    *reinterpret_cast<ushort8*>(&wb[(size_t)idx * 8]) = o;
  } else {
    int i = (b - 8192) * 256 + threadIdx.x;
    float4 a = reinterpret_cast<const float4*>(x)[2 * i];
    float4 c = reinterpret_cast<const float4*>(x)[2 * i + 1];
    ushort8 o;
    o[0] = f2bf(a.x); o[1] = f2bf(a.y); o[2] = f2bf(a.z); o[3] = f2bf(a.w);
    o[4] = f2bf(c.x); o[5] = f2bf(c.y); o[6] = f2bf(c.z); o[7] = f2bf(c.w);
    *reinterpret_cast<ushort8*>(&xb[(size_t)i * 8]) = o;
  }
}

// outlier add via HW packed-bf16 atomic: one fire-and-forget instruction per
// outlier (vs CAS read+RMW loop). Other lane adds +0.0 bf16 (exact identity;
// dequant never produces -0). Duplicates accumulate atomically.
__global__ __launch_bounds__(256) void scatter_pk_kernel(
    const float* __restrict__ vals, const int* __restrict__ rows,
    const int* __restrict__ cols, unsigned short* __restrict__ wb, int nnz) {
  int i = blockIdx.x * 256 + threadIdx.x;
  if (i >= nnz) return;
  size_t idx = (size_t)rows[i] * IN_DIM + cols[i];
  unsigned int* word = (unsigned int*)(wb + (idx & ~(size_t)1));
  unsigned short h = f2bf(vals[i]);
  unsigned int data = (idx & 1) ? ((unsigned)h << 16) : (unsigned)h;
  asm volatile("global_atomic_pk_add_bf16 %0, %1, off"
               :: "v"(word), "v"(data) : "memory");
}

// ---------------- GEMM: C[N][O] = A[N][K] * B[O][K]^T, 256x256 tile --------
// 8 waves, QUADRANT schedule (m201's 12/4/4/4 read distribution): B-frags
// for the FULL K=64 are read once per K-tile (8 ds_read_b128, held in
// 32 VGPR); A streams 2 frags x 2 kh per quadrant phase (4 reads). So
// phases 2-4 are MFMA-bound (384cy DS < 620cy MFMA -> DS hides under
// MFMA); only phase 1 pays a DS-bound cost. Round-8's even 8/4/8/4 split
// made half the phases DS-bound (measured 4714 cy/K-tile = serialized).
//
// Ledger (per-wave FIFO, 2 loads/slab/wave; stages all -> buf^1):
//   P1: STAGE B-kh0(t+1); vmcnt(2) [queue = B0,B1,A0,A1(t) + B0(t+1) = 10
//       loads -> completes all 4 slabs of t, keeps B0(t+1) in flight];
//       barrier; read B-all(8) + A-q0(4) POST-barrier (RAW); MFMA q0.
//   P2: read A-q1 pre-barrier; STAGE B-kh1(t+1); MFMA q1.
//   P3: read A-q2; STAGE A-kh0(t+1); MFMA q2.
//   P4: read A-q3; STAGE A-kh1(t+1); MFMA q3.
// WAR: buf^1's slabs fully read+drained (lgkm(0)) phases before re-stage.
// Never drains vmcnt to 0 in-loop (T4). Swizzle sigma(row)=(row>>1)&3 on
// 16B slots, both-sides (rule #21) — 0 bank conflicts (round 3 measured).

#define SB(buf, op, kh) ((((buf) * 4) + ((op) * 2) + (kh)) * 16384)

#define STAGE(buf, op, kh, kt)                                              \
  do {                                                                      \
    const unsigned short* gsrc_ =                                           \
        (op) ? (const unsigned short*)((const char*)gA + dBA) : gA;         \
    const unsigned short* g_ = gsrc_ + (kt) * 64 + (kh) * 32;               \
    unsigned short* l_ =                                                    \
        (unsigned short*)((char*)lds + SB(buf, op, kh)) + wave * 512;       \
    async_copy16(g_, l_);                                                   \
    async_copy16(g_ + 128 * IN_DIM, l_ + 4096);                             \
  } while (0)

#define MFMA_ __builtin_amdgcn_mfma_f32_16x16x32_bf16

// A quadrant Q: frags 2Q,2Q+1 from both kh slabs (4 reads)
#define LDAQ(BUF, Q)                                                        \
  a00 = *(const bf16x8*)(ldsc + (laneA + SB(BUF, 0, 0) + (2*(Q)) * 1024));  \
  a01 = *(const bf16x8*)(ldsc + (laneA + SB(BUF, 0, 0) + (2*(Q)+1) * 1024));\
  a10 = *(const bf16x8*)(ldsc + (laneA + SB(BUF, 0, 1) + (2*(Q)) * 1024));  \
  a11 = *(const bf16x8*)(ldsc + (laneA + SB(BUF, 0, 1) + (2*(Q)+1) * 1024))

#define LDB4(d0, d1, d2, d3, BUF, KS)                                       \
  d0 = *(const bf16x8*)(ldsc + (laneB + SB(BUF, 1, KS) + 0));               \
  d1 = *(const bf16x8*)(ldsc + (laneB + SB(BUF, 1, KS) + 1024));            \
  d2 = *(const bf16x8*)(ldsc + (laneB + SB(BUF, 1, KS) + 2048));            \
  d3 = *(const bf16x8*)(ldsc + (laneB + SB(BUF, 1, KS) + 3072))

// 16 MFMA: quadrant Q x K=64. kh0 cluster then kh1 (acc reuse distance 8).
#define MMQ(Q)                                                              \
  acc[2*(Q)+0][0] = MFMA_(a00, b00, acc[2*(Q)+0][0], 0, 0, 0);              \
  acc[2*(Q)+0][1] = MFMA_(a00, b01, acc[2*(Q)+0][1], 0, 0, 0);              \
  acc[2*(Q)+0][2] = MFMA_(a00, b02, acc[2*(Q)+0][2], 0, 0, 0);              \
  acc[2*(Q)+0][3] = MFMA_(a00, b03, acc[2*(Q)+0][3], 0, 0, 0);              \
  acc[2*(Q)+1][0] = MFMA_(a01, b00, acc[2*(Q)+1][0], 0, 0, 0);              \
  acc[2*(Q)+1][1] = MFMA_(a01, b01, acc[2*(Q)+1][1], 0, 0, 0);              \
  acc[2*(Q)+1][2] = MFMA_(a01, b02, acc[2*(Q)+1][2], 0, 0, 0);              \
  acc[2*(Q)+1][3] = MFMA_(a01, b03, acc[2*(Q)+1][3], 0, 0, 0);              \
  acc[2*(Q)+0][0] = MFMA_(a10, b10, acc[2*(Q)+0][0], 0, 0, 0);              \
  acc[2*(Q)+0][1] = MFMA_(a10, b11, acc[2*(Q)+0][1], 0, 0, 0);              \
  acc[2*(Q)+0][2] = MFMA_(a10, b12, acc[2*(Q)+0][2], 0, 0, 0);              \
  acc[2*(Q)+0][3] = MFMA_(a10, b13, acc[2*(Q)+0][3], 0, 0, 0);              \
  acc[2*(Q)+1][0] = MFMA_(a11, b10, acc[2*(Q)+1][0], 0, 0, 0);              \
  acc[2*(Q)+1][1] = MFMA_(a11, b11, acc[2*(Q)+1][1], 0, 0, 0);              \
  acc[2*(Q)+1][2] = MFMA_(a11, b12, acc[2*(Q)+1][2], 0, 0, 0);              \
  acc[2*(Q)+1][3] = MFMA_(a11, b13, acc[2*(Q)+1][3], 0, 0, 0)

#define PH1(BUF, tS)                                                        \
  do {                                                                      \
    STAGE(1 - (BUF), 1, 0, tS);                                             \
    asm volatile("s_waitcnt vmcnt(2)" ::: "memory");                        \
    __builtin_amdgcn_s_barrier();                                           \
    LDB4(b00, b01, b02, b03, BUF, 0);                                       \
    LDB4(b10, b11, b12, b13, BUF, 1);                                       \
    LDAQ(BUF, 0);                                                           \
    asm volatile("s_waitcnt lgkmcnt(0)" ::: "memory");                      \
    __builtin_amdgcn_s_setprio(1);                                          \
    MMQ(0);                                                                 \
    __builtin_amdgcn_s_setprio(0);                                          \
    __builtin_amdgcn_s_barrier();                                           \
  } while (0)

#define PHQ(BUF, Q, OP, KH, tS)                                             \
  do {                                                                      \
    LDAQ(BUF, Q);                                                           \
    STAGE(1 - (BUF), OP, KH, tS);                                           \
    __builtin_amdgcn_s_barrier();                                           \
    asm volatile("s_waitcnt lgkmcnt(0)" ::: "memory");                      \
    __builtin_amdgcn_s_setprio(1);                                          \
    MMQ(Q);                                                                 \
    __builtin_amdgcn_s_setprio(0);                                          \
    __builtin_amdgcn_s_barrier();                                           \
  } while (0)

#define MINC(x) ((x) < NT ? (x) : (NT - 1))

#define TILE(BUF, t)                                                        \
  do {                                                                      \
    PH1(BUF, MINC((t) + 1));                                                \
    PHQ(BUF, 1, 1, 1, MINC((t) + 1));                                       \
    PHQ(BUF, 2, 0, 0, MINC((t) + 1));                                       \
    PHQ(BUF, 3, 0, 1, MINC((t) + 1));                                       \
  } while (0)

__global__ __launch_bounds__(512, 2) void gemm_kernel(
    const unsigned short* __restrict__ A,  // [4096][4096] bf16 (x)
    const unsigned short* __restrict__ B,  // [4096][4096] bf16 (W)
    float* __restrict__ C) {               // [4096][4096] fp32
  __shared__ __align__(16) unsigned short lds[65536];  // 128 KiB
  const char* ldsc = (const char*)lds;

  // 4x8 (bm x bn) super-tile per XCD for L2 locality; 256%8==0 -> bijective
  const int bid = blockIdx.x;
  const int xcd = bid & 7, i_ = bid >> 3;
  const int bm = (xcd >> 1) * 4 + (i_ >> 3);
  const int bn = (xcd & 1) * 8 + (i_ & 7);
  const int m0 = bm * 256, n0 = bn * 256;

  const int tid = threadIdx.x;
  const int wave = tid >> 6, lane = tid & 63;
  const int wm = wave >> 2, wn = wave & 3;  // 2M x 4N wave grid
  const int lrow = lane & 15, lk = lane >> 4;

  // staging: chunk0 = tid -> (row=tid>>2, phys slot=tid&3); chunk1 = +128.
  // SOURCE slot pre-swizzled so swizzled-read sees correct data (rule #21).
  const int r0 = tid >> 2, s0 = tid & 3;
  const int s0s = s0 ^ ((r0 >> 1) & 3);
  const unsigned short* gA = A + (size_t)(m0 + r0) * IN_DIM + s0s * 8;
  // uniform (SGPR) byte delta to the B staging source
  const ptrdiff_t dBA = ((const char*)B - (const char*)A) +
                        (ptrdiff_t)(n0 - m0) * IN_DIM * 2;

  // per-lane LDS byte bases (swizzle folded into lks)
  const int lks = lk ^ ((lrow >> 1) & 3);
  const int laneA = (wm * 128 + lrow) * 64 + lks * 16;
  const int laneB = (wn * 64 + lrow) * 64 + lks * 16;

  f32x4 acc[8][4];
#pragma unroll
  for (int mi = 0; mi < 8; ++mi)
#pragma unroll
    for (int ni = 0; ni < 4; ++ni) acc[mi][ni] = (f32x4){0.f, 0.f, 0.f, 0.f};

  bf16x8 b00, b01, b02, b03, b10, b11, b12, b13;  // B K=64, per-tile
  bf16x8 a00, a01, a10, a11;                      // A quadrant, per-phase

  // prologue: all 4 slabs of tile 0 -> buf0 (FIFO order B0,B1,A0,A1 matches
  // the steady-state wait arithmetic; separators pin issue order).
  STAGE(0, 1, 0, 0);
  asm volatile("" ::: "memory");
  STAGE(0, 1, 1, 0);
  asm volatile("" ::: "memory");
  STAGE(0, 0, 0, 0);
  asm volatile("" ::: "memory");
  STAGE(0, 0, 1, 0);
  // no wait here: PH1(t=0)'s vmcnt(2)+barrier gates the first reads.

#pragma unroll 1
  for (int p = 0; p < NT / 2; ++p) {
    TILE(0, 2 * p);
    TILE(1, 2 * p + 1);
  }
  // drain DMA before epilogue/endpgm
  asm volatile("s_waitcnt vmcnt(0) lgkmcnt(0)" ::: "memory");

  // epilogue: D mapping col=lane&15, row=(lane>>4)*4+reg
#pragma unroll
  for (int mi = 0; mi < 8; ++mi)
#pragma unroll
    for (int ni = 0; ni < 4; ++ni) {
      int m = m0 + wm * 128 + mi * 16 + lk * 4;
      int n = n0 + wn * 64 + ni * 16 + lrow;
      float* cp = &C[(size_t)m * OUT_DIM + n];
#pragma unroll
      for (int r = 0; r < 4; ++r) cp[(size_t)r * OUT_DIM] = acc[mi][ni][r];
    }
}

// ---------------- launch ----------------

extern "C" void kernel_launch(void* const* d_in, const int* in_sizes, int n_in,
                              void* d_out, int out_size, void* d_ws, size_t ws_size,
                              hipStream_t stream) {
  const float* x      = (const float*)d_in[0];
  const int*   packed = (const int*)d_in[1];
  const float* scales = (const float*)d_in[2];
  const float* vals   = (const float*)d_in[3];
  const int*   rows   = (const int*)d_in[4];
  const int*   cols   = (const int*)d_in[5];
  float* out = (float*)d_out;

  const int nnz = in_sizes[3];

  // ws: [0,32MB) W bf16 | [32,64MB) X bf16
  char* ws = (char*)d_ws;
  const size_t MB = 1024 * 1024;
  unsigned short* Wb = (unsigned short*)ws;
  unsigned short* Xb = (unsigned short*)(ws + 32 * MB);

  // 1) merged dequant (blocks 0-8191) + x cvt (blocks 8192-16383)
  prep_kernel<<<16384, 256, 0, stream>>>(packed, scales, Wb, x, Xb);
  // 2) outlier residual via HW packed-bf16 atomic add
  scatter_pk_kernel<<<(nnz + 255) / 256, 256, 0, stream>>>(vals, rows, cols, Wb, nnz);
  // 3) bf16 MFMA GEMM: out = Xb (4096x4096) * Wb^T
  gemm_kernel<<<256, 512, 0, stream>>>(Xb, Wb, out);
}